// Round 19
// baseline (218.028 us; speedup 1.0000x reference)
//
#include <hip/hip_runtime.h>
#include <hip/hip_bf16.h>

#define F 64
#define NB 8
#define NE 10
#define GSEG 4
#define EPW 256    // energy-partial spread width (contention relief)
#define NTAB 2048  // radial-table steps; NTAB+1 entries cover r in [0,5]

typedef __attribute__((ext_vector_type(8))) short short8v;
typedef __attribute__((ext_vector_type(4))) float float4v;

__device__ __forceinline__ float silu(float x) {
    return x / (1.0f + __expf(-x));
}

// wave broadcast: v_readlane -> SGPR, feeds FMA as scalar operand
__device__ __forceinline__ float bcast(float v, int lane) {
    return __uint_as_float(__builtin_amdgcn_readlane(__float_as_uint(v), lane));
}

__device__ __forceinline__ unsigned short f2bf(float x) {   // RNE bf16
    unsigned int u = __float_as_uint(x);
    u += 0x7FFFu + ((u >> 16) & 1u);
    return (unsigned short)(u >> 16);
}

// ---------------------------------------------------------------------------
// Kernel 1 (merged): [0,nodeBlocks) per-node init (S0, e0, deg=0, pos4,
// spec[n] = one-hot argmax of node_attrs); [nodeBlocks, +tabBlocks) radial
// table; [.., +wbBlocks) Wmix -> bf16 Wbt[t][l][g][f] (1/AVG_NEIGH folded).
// ---------------------------------------------------------------------------
__global__ __launch_bounds__(256) void init_and_tables(
    const float* __restrict__ node_attrs, const float* __restrict__ AE,
    const float* __restrict__ W_embed, const int* __restrict__ batch,
    const float* __restrict__ pos,
    float* __restrict__ S0, float* __restrict__ epart,
    int* __restrict__ deg, float4* __restrict__ pos4,
    int* __restrict__ spec, int N, int nodeBlocks,
    const float* __restrict__ Wr0, const float* __restrict__ Wr1,
    const float* __restrict__ Wr2, float* __restrict__ Tab,
    const float* __restrict__ Wmix, unsigned short* __restrict__ Wbt,
    int tabBlocks)
{
    int w = threadIdx.x >> 6, lane = threadIdx.x & 63;

    if (blockIdx.x < (unsigned)nodeBlocks) {
        int n = blockIdx.x * 4 + w;
        if (n >= N) return;
        float sc = 0.0f, e0 = 0.0f;
        int sp = 0;
        #pragma unroll
        for (int e = 0; e < NE; e++) {
            float a = node_attrs[n * NE + e];   // wave-uniform
            sc = fmaf(a, W_embed[e * F + lane], sc);
            e0 = fmaf(a, AE[e], e0);
            if (a > 0.5f) sp = e;
        }
        S0[(size_t)n * F + lane] = sc;
        if (lane == 0) {
            deg[n] = 0;
            spec[n] = sp;
            pos4[n] = make_float4(pos[n * 3], pos[n * 3 + 1], pos[n * 3 + 2], 0.f);
            atomicAdd(&epart[batch[n] * EPW + (n & (EPW - 1))], e0);
        }
        return;
    }

    if (blockIdx.x >= (unsigned)(nodeBlocks + tabBlocks)) {
        // ---- Wbt prep: Wbt[t][l][g][f] = Wmix[t][l][f][g] / 16, bf16 ----
        int i = (blockIdx.x - nodeBlocks - tabBlocks) * 256 + threadIdx.x;
        if (i >= 2 * 3 * 4096) return;
        int tl = i >> 12;            // t*3 + l
        int gf = i & 4095;
        int g = gf >> 6, f = gf & 63;
        Wbt[i] = f2bf(Wmix[(size_t)(tl * 64 + f) * 64 + g] * 0.0625f);
        return;
    }

    // ---- table-build section ----
    const int blocksPerTab = (NTAB + 1 + 3) / 4;   // 513
    int bid = blockIdx.x - nodeBlocks;
    int tab = bid / blocksPerTab;
    int eidx = (bid - tab * blocksPerTab) * 4 + w;
    if (eidx > NTAB) return;
    const float* W0 = Wr0 + tab * 512;
    const float* W1 = Wr1 + tab * 4096;
    const float* W2 = Wr2 + tab * 12288;

    float r = (float)eidx * (5.0f / NTAB);
    float rs = fmaxf(r, 1e-6f);
    float s1, c1;
    __sincosf(0.6283185307179586f * rs, &s1, &c1);   // pi*rs/5
    float u = r * 0.2f;
    float u2 = u * u, u4 = u2 * u2, u5 = u4 * u, u6 = u5 * u, u7 = u6 * u;
    float fc = 1.0f - 21.0f * u5 + 35.0f * u6 - 15.0f * u7;
    float pref = 0.6324555320336759f / rs * fc;      // sqrt(2/5)
    float ef[NB];
    {
        float sp = 0.0f, sc_ = s1, tc = 2.0f * c1;
        #pragma unroll
        for (int k = 0; k < NB; k++) {
            ef[k] = pref * sc_;
            float sn = tc * sc_ - sp;
            sp = sc_; sc_ = sn;
        }
    }

    float a1 = 0.0f;
    #pragma unroll
    for (int k = 0; k < NB; k++) a1 = fmaf(ef[k], W0[k * 64 + lane], a1);
    float h1 = silu(a1);

    float a2 = 0.0f;
    #pragma unroll 8
    for (int k = 0; k < 64; k++)
        a2 = fmaf(bcast(h1, k), W1[k * 64 + lane], a2);
    float h2 = silu(a2);

    float w0 = 0.f, w1 = 0.f, w2 = 0.f;
    #pragma unroll 8
    for (int k = 0; k < 64; k++) {
        float hk = bcast(h2, k);
        const float* wr = W2 + k * 192 + lane * 3;
        w0 = fmaf(hk, wr[0], w0);
        w1 = fmaf(hk, wr[1], w1);
        w2 = fmaf(hk, wr[2], w2);
    }

    float* Trow = Tab + ((size_t)tab * (NTAB + 1) + eidx) * 192;
    Trow[lane] = w0;
    Trow[64 + lane] = w1;
    Trow[128 + lane] = w2;
}

// ---------------------------------------------------------------------------
// Kernel 2: edge geometry + per-dst degree count. No single-address atomics.
// ---------------------------------------------------------------------------
__global__ __launch_bounds__(256) void edge_prep(
    const float4* __restrict__ pos4, const float* __restrict__ shifts,
    const int* __restrict__ EI, int E,
    float4* __restrict__ geoFull, int* __restrict__ deg)
{
    int e = blockIdx.x * 256 + threadIdx.x;
    if (e >= E) return;
    int s = EI[e], d = EI[E + e];
    float4 pd = pos4[d], ps = pos4[s];
    float vx = pd.x - ps.x + shifts[e * 3 + 0];
    float vy = pd.y - ps.y + shifts[e * 3 + 1];
    float vz = pd.z - ps.z + shifts[e * 3 + 2];
    float len = sqrtf(vx * vx + vy * vy + vz * vz);
    float ls = (len > 1e-6f) ? len : 1.0f;
    float inv = 1.0f / ls;
    geoFull[e] = make_float4(vx * inv, vy * inv, vz * inv, len);
    if (len < 5.0f) atomicAdd(&deg[d], 1);
}

// ---------------------------------------------------------------------------
// Kernel 3: CSR range allocation via block scan (one base atomic per block).
// ---------------------------------------------------------------------------
__global__ __launch_bounds__(256) void alloc_start(
    const int* __restrict__ deg, int* __restrict__ start,
    int* __restrict__ cursor, int* __restrict__ total, int N)
{
    __shared__ int wsum[4];
    __shared__ int gbase;
    int t = threadIdx.x;
    int n = blockIdx.x * 256 + t;
    int lane = t & 63, w = t >> 6;
    int v = (n < N) ? deg[n] : 0;
    int inc = v;
    #pragma unroll
    for (int off = 1; off < 64; off <<= 1) {
        int u = __shfl_up(inc, off);
        if (lane >= off) inc += u;
    }
    if (lane == 63) wsum[w] = inc;
    __syncthreads();
    if (t == 0) {
        int s0 = wsum[0], s1 = wsum[1], s2 = wsum[2], s3 = wsum[3];
        int bs = s0 + s1 + s2 + s3;
        wsum[0] = 0; wsum[1] = s0; wsum[2] = s0 + s1; wsum[3] = s0 + s1 + s2;
        gbase = atomicAdd(total, bs);
    }
    __syncthreads();
    if (n < N) {
        int st = gbase + wsum[w] + (inc - v);   // exclusive prefix
        start[n] = st;
        cursor[n] = st;
    }
}

// ---------------------------------------------------------------------------
// Kernel 4: place geometry + src id into CSR slots.
// ---------------------------------------------------------------------------
__global__ __launch_bounds__(256) void csr_fill(
    const float4* __restrict__ geoFull, const int* __restrict__ EI, int E,
    int* __restrict__ cursor,
    float4* __restrict__ geoS, int* __restrict__ srcS, int EB)
{
    int e = blockIdx.x * 256 + threadIdx.x;
    if (e >= E) return;
    float4 gv = geoFull[e];
    if (gv.w < 5.0f) {
        int d = EI[E + e];
        int p = atomicAdd(&cursor[d], 1);
        if (p < EB) {
            geoS[p] = gv;
            srcS[p] = EI[e];
        }
    }
}

// ---------------------------------------------------------------------------
// Kernel 5 (FUSED gather+mix): block = 1024 = 16 waves = 16 nodes.
// Phase A: per-node edge loop, SOFTWARE-PIPELINED: geoS/srcS of edge i+1
//   prefetched while computing edge i; Sin gather issues at iteration top.
//   (r18 was latency-bound here: VALUBusy 27%, VGPR 28 — headroom.)
// Phase B: waves 0-8 MFMA slices (layouts verified r16-r18, absmax 0.0).
// Phase C: one node per wave; batch/spec/Wprod/residual loads hoisted
//   ABOVE the barriers so their latency hides under Phases A-B.
// No returns before the barriers: inactive waves write zero A rows.
// ---------------------------------------------------------------------------
template <int PHASE>
__global__ __launch_bounds__(1024) void gather_mix(
    const float4* __restrict__ geoS, const int* __restrict__ srcS,
    const float* __restrict__ Tab,
    const int* __restrict__ start, const int* __restrict__ deg,
    const unsigned short* __restrict__ Wbt,    // [3][64][64] bf16 (this t)
    const float* __restrict__ Wprodt, const int* __restrict__ spec,
    const int* __restrict__ batch,
    const float* __restrict__ Wread0, const float* __restrict__ Wm1,
    const float* __restrict__ wm2,
    const float* __restrict__ Sin, float* __restrict__ Sout,
    float* __restrict__ epart, int N)
{
    __shared__ unsigned short Abf[9 * 1088];   // [s][nloc(16)][f(68 pad)] bf16
    __shared__ float Osh[9 * 1088];            // [s][nloc(16)][g(68 pad)] f32

    int t = threadIdx.x;
    int lane = t & 63, w = t >> 6;
    int l15 = lane & 15, quad = lane >> 4;
    int n0 = blockIdx.x * 16;
    int n = n0 + w;
    int g = lane;

    // ---- Phase C prefetch (consumed after the barriers) ----
    int b = 0, sp = 0;
    float resid = 0.0f;
    if (n < N) {
        b = batch[n];
        sp = spec[n];
        if (PHASE == 1) resid = Sin[(size_t)n * F + lane];
    }

    // ---- Phase A: per-node edge accumulation (lane = f), pipelined ----
    float am0 = 0.f, am1 = 0.f, am2_ = 0.f, am3 = 0.f, am4 = 0.f,
          am5 = 0.f, am6 = 0.f, am7 = 0.f, am8 = 0.f;
    if (n < N) {
        int st = start[n], dg = deg[n];
        int iend = st + dg;
        const float s3 = 1.7320508075688772f;
        const float s5h = 1.1180339887498948f;
        const float s15 = 3.8729833462074170f;
        const float s15h = 1.9364916731037085f;
        if (dg > 0) {
            float4 gv = geoS[st];          // preload edge 0
            int srcn = srcS[st];
            for (int i = st; i < iend; i++) {
                float sv = Sin[(size_t)srcn * F + g];   // issue ASAP
                float scaled = gv.w * (NTAB / 5.0f);
                int idx = (int)scaled;
                float fr = scaled - (float)idx;
                const float* T0 = Tab + (size_t)idx * 192;
                float wa = T0[g],        wb = T0[192 + g];
                float wc = T0[64 + g],   wd = T0[256 + g];
                float we = T0[128 + g],  wf_ = T0[320 + g];
                float ux = gv.x, uy = gv.y, uz = gv.z;

                // prefetch next edge while this one's loads are in flight
                if (i + 1 < iend) {
                    gv = geoS[i + 1];
                    srcn = srcS[i + 1];
                }

                float w0 = fmaf(fr, wb - wa, wa);
                float w1 = fmaf(fr, wd - wc, wc);
                float w2 = fmaf(fr, wf_ - we, we);
                float m0 = w0 * sv, m1 = w1 * sv, m2 = w2 * sv;
                am0 += m0;
                am1 = fmaf(m1, s3 * ux, am1);
                am2_ = fmaf(m1, s3 * uy, am2_);
                am3 = fmaf(m1, s3 * uz, am3);
                am4 = fmaf(m2, s15 * ux * uy, am4);
                am5 = fmaf(m2, s15 * uy * uz, am5);
                am6 = fmaf(m2, s5h * (3.0f * uz * uz - 1.0f), am6);
                am7 = fmaf(m2, s15 * ux * uz, am7);
                am8 = fmaf(m2, s15h * (ux * ux - uy * uy), am8);
            }
        }
    }
    int arow = w * 68 + g;
    Abf[0 * 1088 + arow] = f2bf(am0);
    Abf[1 * 1088 + arow] = f2bf(am1);
    Abf[2 * 1088 + arow] = f2bf(am2_);
    Abf[3 * 1088 + arow] = f2bf(am3);
    Abf[4 * 1088 + arow] = f2bf(am4);
    Abf[5 * 1088 + arow] = f2bf(am5);
    Abf[6 * 1088 + arow] = f2bf(am6);
    Abf[7 * 1088 + arow] = f2bf(am7);
    Abf[8 * 1088 + arow] = f2bf(am8);

    // Wprod row prefetch (depends on sp; in flight across the barriers)
    float wp0 = 0.f, wp1 = 0.f, wp2 = 0.f;
    if (n < N) {
        const float* W = Wprodt + (sp * F + lane) * 3;
        wp0 = W[0]; wp1 = W[1]; wp2 = W[2];
    }
    __syncthreads();

    // ---- Phase B: MFMA mixing, waves 0-8 ----
    if (w < 9) {
        int s = w;
        int l = (s == 0) ? 0 : ((s < 4) ? 1 : 2);
        const unsigned short* Bp = Wbt + l * 4096 + (size_t)l15 * 64;
        const unsigned short* Ar = &Abf[s * 1088 + l15 * 68];
        short8v a0 = *(const short8v*)(Ar + quad * 8);
        short8v a1 = *(const short8v*)(Ar + 32 + quad * 8);
        #pragma unroll
        for (int nt = 0; nt < 4; nt++) {
            short8v b0 = *(const short8v*)(Bp + nt * 1024 + quad * 8);
            short8v b1 = *(const short8v*)(Bp + nt * 1024 + 32 + quad * 8);
            float4v acc = {0.f, 0.f, 0.f, 0.f};
            acc = __builtin_amdgcn_mfma_f32_16x16x32_bf16(a0, b0, acc, 0, 0, 0);
            acc = __builtin_amdgcn_mfma_f32_16x16x32_bf16(a1, b1, acc, 0, 0, 0);
            #pragma unroll
            for (int r = 0; r < 4; r++)
                Osh[s * 1088 + (quad * 4 + r) * 68 + nt * 16 + l15] = acc[r];
        }
    }
    __syncthreads();

    // ---- Phase C: epilogue, one node per wave ----
    if (n >= N) return;
    float bb[9];
    #pragma unroll
    for (int s = 0; s < 9; s++) bb[s] = Osh[s * 1088 + w * 68 + lane];

    float p1 = bb[0];
    float p2 = 0.f;
    #pragma unroll
    for (int s = 0; s < 9; s++) p2 = fmaf(bb[s], bb[s], p2);
    float scale = wp0 + wp1 * p1 + wp2 * p2;
    float sc0 = bb[0] * scale;

    if (PHASE == 0) {
        Sout[(size_t)n * F + lane] = sc0;
        float vv = sc0 * Wread0[lane];
        #pragma unroll
        for (int off = 32; off > 0; off >>= 1) vv += __shfl_xor(vv, off);
        if (lane == 0) atomicAdd(&epart[b * EPW + (n & (EPW - 1))], vv);
    } else {
        sc0 += resid;                    // residual (prev channel-0)
        int gi = lane & 15;
        float acc = 0.0f;
        #pragma unroll 8
        for (int k = 0; k < 64; k++)
            acc = fmaf(bcast(sc0, k), Wm1[k * 16 + gi], acc);
        float vv = (lane < 16) ? silu(acc) * wm2[gi] : 0.0f;
        #pragma unroll
        for (int off = 32; off > 0; off >>= 1) vv += __shfl_xor(vv, off);
        if (lane == 0) atomicAdd(&epart[b * EPW + (n & (EPW - 1))], vv);
    }
}

// ---------------------------------------------------------------------------
// Kernel 6: final energy reduction; sole writer of d_out.
// ---------------------------------------------------------------------------
__global__ __launch_bounds__(256) void reduce_energy(
    const float* __restrict__ epart, float* __restrict__ out)
{
    int t = threadIdx.x;
    __shared__ float ps[GSEG][4];
    for (int b = 0; b < GSEG; b++) {
        float v = epart[b * EPW + t];
        #pragma unroll
        for (int off = 32; off > 0; off >>= 1) v += __shfl_xor(v, off);
        if ((t & 63) == 0) ps[b][t >> 6] = v;
    }
    __syncthreads();
    if (t < GSEG) out[t] = ps[t][0] + ps[t][1] + ps[t][2] + ps[t][3];
}

extern "C" void kernel_launch(void* const* d_in, const int* in_sizes, int n_in,
                              void* d_out, int out_size, void* d_ws, size_t ws_size,
                              hipStream_t stream) {
    const float* positions  = (const float*)d_in[0];
    const float* node_attrs = (const float*)d_in[1];
    const float* shifts     = (const float*)d_in[2];
    // d_in[3] charges: unused (charge_density never feeds energy)
    const int*   edge_index = (const int*)d_in[4];
    const int*   batch      = (const int*)d_in[5];
    const float* AE         = (const float*)d_in[6];
    const float* W_embed    = (const float*)d_in[7];
    const float* Wr0        = (const float*)d_in[8];
    const float* Wr1        = (const float*)d_in[9];
    const float* Wr2        = (const float*)d_in[10];
    const float* Wmix       = (const float*)d_in[11];
    const float* Wprod      = (const float*)d_in[12];
    const float* Wread0     = (const float*)d_in[13];
    const float* Wm1        = (const float*)d_in[14];
    const float* wm2        = (const float*)d_in[15];
    // d_in[16] Wq: unused

    int N = in_sizes[0] / 3;
    int E = in_sizes[4] / 2;
    int EB = E / 8;
    float* out = (float*)d_out;

    char* ws = (char*)d_ws;
    size_t off = 0;
    auto alignup = [](size_t v) { return (v + 255) & ~(size_t)255; };
    float4* geoFull = (float4*)(ws + off); off = alignup(off + (size_t)E * sizeof(float4));
    float4* geoS  = (float4*)(ws + off); off = alignup(off + (size_t)EB * sizeof(float4));
    float4* pos4  = (float4*)(ws + off); off = alignup(off + (size_t)N * sizeof(float4));
    float*  S0    = (float*)(ws + off);  off = alignup(off + (size_t)N * F * sizeof(float));
    float*  S1    = (float*)(ws + off);  off = alignup(off + (size_t)N * F * sizeof(float));
    int*    srcS  = (int*)(ws + off);    off = alignup(off + (size_t)EB * sizeof(int));
    int*    deg   = (int*)(ws + off);    off = alignup(off + (size_t)N * sizeof(int));
    int*    start = (int*)(ws + off);    off = alignup(off + (size_t)N * sizeof(int));
    int*    cursor= (int*)(ws + off);    off = alignup(off + (size_t)N * sizeof(int));
    int*    spec  = (int*)(ws + off);    off = alignup(off + (size_t)N * sizeof(int));
    // epart + total share one memset region: total INSIDE the memset range
    // (r15 bug: alignup pushed total past the memset -> poison -> OOB).
    float*  epart = (float*)(ws + off);
    int*    total = (int*)(ws + off + GSEG * EPW * sizeof(float));
    off = alignup(off + GSEG * EPW * sizeof(float) + 128);
    float*  Tab   = (float*)(ws + off);
    off = alignup(off + (size_t)2 * (NTAB + 1) * 192 * sizeof(float));
    unsigned short* Wbt = (unsigned short*)(ws + off);
    off = alignup(off + (size_t)2 * 3 * 4096 * sizeof(unsigned short));
    // total ~22 MB

    hipMemsetAsync(epart, 0, GSEG * EPW * sizeof(float) + 128, stream); // + total

    int nodeBlocks4 = (N + 3) / 4;
    int nodeBlocks256 = (N + 255) / 256;
    int edgeBlocks = (E + 255) / 256;
    int tabBlocks = 2 * ((NTAB + 1 + 3) / 4);
    int wbBlocks = (2 * 3 * 4096 + 255) / 256;
    int gmBlocks = (N + 15) / 16;
    size_t tabStride = (size_t)(NTAB + 1) * 192;

    init_and_tables<<<nodeBlocks4 + tabBlocks + wbBlocks, 256, 0, stream>>>(
        node_attrs, AE, W_embed, batch, positions,
        S0, epart, deg, pos4, spec, N, nodeBlocks4,
        Wr0, Wr1, Wr2, Tab, Wmix, Wbt, tabBlocks);
    edge_prep<<<edgeBlocks, 256, 0, stream>>>(pos4, shifts, edge_index, E,
                                              geoFull, deg);
    alloc_start<<<nodeBlocks256, 256, 0, stream>>>(deg, start, cursor, total, N);
    csr_fill<<<edgeBlocks, 256, 0, stream>>>(geoFull, edge_index, E,
                                             cursor, geoS, srcS, EB);

    // t = 0
    gather_mix<0><<<gmBlocks, 1024, 0, stream>>>(geoS, srcS, Tab, start, deg,
                                                 Wbt, Wprod, spec, batch,
                                                 Wread0, Wm1, wm2,
                                                 S0, S1, epart, N);
    // t = 1
    gather_mix<1><<<gmBlocks, 1024, 0, stream>>>(geoS, srcS, Tab + tabStride,
                                                 start, deg,
                                                 Wbt + 3 * 4096,
                                                 Wprod + NE * F * 3, spec, batch,
                                                 Wread0, Wm1, wm2,
                                                 S1, S1, epart, N);

    reduce_energy<<<1, 256, 0, stream>>>(epart, out);
}

// Round 20
// 210.963 us; speedup vs baseline: 1.0335x; 1.0335x over previous
//
#include <hip/hip_runtime.h>
#include <hip/hip_bf16.h>

#define F 64
#define NB 8
#define NE 10
#define GSEG 4
#define EPW 256    // energy-partial spread width (contention relief)
#define NTAB 2048  // radial-table steps; NTAB+1 entries cover r in [0,5]

typedef __attribute__((ext_vector_type(8))) short short8v;
typedef __attribute__((ext_vector_type(4))) float float4v;

__device__ __forceinline__ float silu(float x) {
    return x / (1.0f + __expf(-x));
}

// wave broadcast: v_readlane -> SGPR, feeds FMA as scalar operand
__device__ __forceinline__ float bcast(float v, int lane) {
    return __uint_as_float(__builtin_amdgcn_readlane(__float_as_uint(v), lane));
}

__device__ __forceinline__ unsigned short f2bf(float x) {   // RNE bf16
    unsigned int u = __float_as_uint(x);
    u += 0x7FFFu + ((u >> 16) & 1u);
    return (unsigned short)(u >> 16);
}

// ---------------------------------------------------------------------------
// Kernel 1 (merged): [0,nodeBlocks) per-node init (S0, e0, deg=0, pos4,
// spec[n] = one-hot argmax of node_attrs); [nodeBlocks, +tabBlocks) radial
// table; [.., +wbBlocks) Wmix -> bf16 Wbt[t][l][g][f] (1/AVG_NEIGH folded).
// ---------------------------------------------------------------------------
__global__ __launch_bounds__(256) void init_and_tables(
    const float* __restrict__ node_attrs, const float* __restrict__ AE,
    const float* __restrict__ W_embed, const int* __restrict__ batch,
    const float* __restrict__ pos,
    float* __restrict__ S0, float* __restrict__ epart,
    int* __restrict__ deg, float4* __restrict__ pos4,
    int* __restrict__ spec, int N, int nodeBlocks,
    const float* __restrict__ Wr0, const float* __restrict__ Wr1,
    const float* __restrict__ Wr2, float* __restrict__ Tab,
    const float* __restrict__ Wmix, unsigned short* __restrict__ Wbt,
    int tabBlocks)
{
    int w = threadIdx.x >> 6, lane = threadIdx.x & 63;

    if (blockIdx.x < (unsigned)nodeBlocks) {
        int n = blockIdx.x * 4 + w;
        if (n >= N) return;
        float sc = 0.0f, e0 = 0.0f;
        int sp = 0;
        #pragma unroll
        for (int e = 0; e < NE; e++) {
            float a = node_attrs[n * NE + e];   // wave-uniform
            sc = fmaf(a, W_embed[e * F + lane], sc);
            e0 = fmaf(a, AE[e], e0);
            if (a > 0.5f) sp = e;
        }
        S0[(size_t)n * F + lane] = sc;
        if (lane == 0) {
            deg[n] = 0;
            spec[n] = sp;
            pos4[n] = make_float4(pos[n * 3], pos[n * 3 + 1], pos[n * 3 + 2], 0.f);
            atomicAdd(&epart[batch[n] * EPW + (n & (EPW - 1))], e0);
        }
        return;
    }

    if (blockIdx.x >= (unsigned)(nodeBlocks + tabBlocks)) {
        // ---- Wbt prep: Wbt[t][l][g][f] = Wmix[t][l][f][g] / 16, bf16 ----
        int i = (blockIdx.x - nodeBlocks - tabBlocks) * 256 + threadIdx.x;
        if (i >= 2 * 3 * 4096) return;
        int tl = i >> 12;            // t*3 + l
        int gf = i & 4095;
        int g = gf >> 6, f = gf & 63;
        Wbt[i] = f2bf(Wmix[(size_t)(tl * 64 + f) * 64 + g] * 0.0625f);
        return;
    }

    // ---- table-build section ----
    const int blocksPerTab = (NTAB + 1 + 3) / 4;   // 513
    int bid = blockIdx.x - nodeBlocks;
    int tab = bid / blocksPerTab;
    int eidx = (bid - tab * blocksPerTab) * 4 + w;
    if (eidx > NTAB) return;
    const float* W0 = Wr0 + tab * 512;
    const float* W1 = Wr1 + tab * 4096;
    const float* W2 = Wr2 + tab * 12288;

    float r = (float)eidx * (5.0f / NTAB);
    float rs = fmaxf(r, 1e-6f);
    float s1, c1;
    __sincosf(0.6283185307179586f * rs, &s1, &c1);   // pi*rs/5
    float u = r * 0.2f;
    float u2 = u * u, u4 = u2 * u2, u5 = u4 * u, u6 = u5 * u, u7 = u6 * u;
    float fc = 1.0f - 21.0f * u5 + 35.0f * u6 - 15.0f * u7;
    float pref = 0.6324555320336759f / rs * fc;      // sqrt(2/5)
    float ef[NB];
    {
        float sp = 0.0f, sc_ = s1, tc = 2.0f * c1;
        #pragma unroll
        for (int k = 0; k < NB; k++) {
            ef[k] = pref * sc_;
            float sn = tc * sc_ - sp;
            sp = sc_; sc_ = sn;
        }
    }

    float a1 = 0.0f;
    #pragma unroll
    for (int k = 0; k < NB; k++) a1 = fmaf(ef[k], W0[k * 64 + lane], a1);
    float h1 = silu(a1);

    float a2 = 0.0f;
    #pragma unroll 8
    for (int k = 0; k < 64; k++)
        a2 = fmaf(bcast(h1, k), W1[k * 64 + lane], a2);
    float h2 = silu(a2);

    float w0 = 0.f, w1 = 0.f, w2 = 0.f;
    #pragma unroll 8
    for (int k = 0; k < 64; k++) {
        float hk = bcast(h2, k);
        const float* wr = W2 + k * 192 + lane * 3;
        w0 = fmaf(hk, wr[0], w0);
        w1 = fmaf(hk, wr[1], w1);
        w2 = fmaf(hk, wr[2], w2);
    }

    float* Trow = Tab + ((size_t)tab * (NTAB + 1) + eidx) * 192;
    Trow[lane] = w0;
    Trow[64 + lane] = w1;
    Trow[128 + lane] = w2;
}

// ---------------------------------------------------------------------------
// Kernel 2: edge geometry + per-dst degree count. No single-address atomics.
// ---------------------------------------------------------------------------
__global__ __launch_bounds__(256) void edge_prep(
    const float4* __restrict__ pos4, const float* __restrict__ shifts,
    const int* __restrict__ EI, int E,
    float4* __restrict__ geoFull, int* __restrict__ deg)
{
    int e = blockIdx.x * 256 + threadIdx.x;
    if (e >= E) return;
    int s = EI[e], d = EI[E + e];
    float4 pd = pos4[d], ps = pos4[s];
    float vx = pd.x - ps.x + shifts[e * 3 + 0];
    float vy = pd.y - ps.y + shifts[e * 3 + 1];
    float vz = pd.z - ps.z + shifts[e * 3 + 2];
    float len = sqrtf(vx * vx + vy * vy + vz * vz);
    float ls = (len > 1e-6f) ? len : 1.0f;
    float inv = 1.0f / ls;
    geoFull[e] = make_float4(vx * inv, vy * inv, vz * inv, len);
    if (len < 5.0f) atomicAdd(&deg[d], 1);
}

// ---------------------------------------------------------------------------
// Kernel 3: CSR range allocation via block scan (one base atomic per block).
// ---------------------------------------------------------------------------
__global__ __launch_bounds__(256) void alloc_start(
    const int* __restrict__ deg, int* __restrict__ start,
    int* __restrict__ cursor, int* __restrict__ total, int N)
{
    __shared__ int wsum[4];
    __shared__ int gbase;
    int t = threadIdx.x;
    int n = blockIdx.x * 256 + t;
    int lane = t & 63, w = t >> 6;
    int v = (n < N) ? deg[n] : 0;
    int inc = v;
    #pragma unroll
    for (int off = 1; off < 64; off <<= 1) {
        int u = __shfl_up(inc, off);
        if (lane >= off) inc += u;
    }
    if (lane == 63) wsum[w] = inc;
    __syncthreads();
    if (t == 0) {
        int s0 = wsum[0], s1 = wsum[1], s2 = wsum[2], s3 = wsum[3];
        int bs = s0 + s1 + s2 + s3;
        wsum[0] = 0; wsum[1] = s0; wsum[2] = s0 + s1; wsum[3] = s0 + s1 + s2;
        gbase = atomicAdd(total, bs);
    }
    __syncthreads();
    if (n < N) {
        int st = gbase + wsum[w] + (inc - v);   // exclusive prefix
        start[n] = st;
        cursor[n] = st;
    }
}

// ---------------------------------------------------------------------------
// Kernel 4: place geometry + src id into CSR slots.
// ---------------------------------------------------------------------------
__global__ __launch_bounds__(256) void csr_fill(
    const float4* __restrict__ geoFull, const int* __restrict__ EI, int E,
    int* __restrict__ cursor,
    float4* __restrict__ geoS, int* __restrict__ srcS, int EB)
{
    int e = blockIdx.x * 256 + threadIdx.x;
    if (e >= E) return;
    float4 gv = geoFull[e];
    if (gv.w < 5.0f) {
        int d = EI[E + e];
        int p = atomicAdd(&cursor[d], 1);
        if (p < EB) {
            geoS[p] = gv;
            srcS[p] = EI[e];
        }
    }
}

// ---------------------------------------------------------------------------
// Kernel 5 (FUSED gather+mix): block = 512 = 8 waves, 16-node tile.
// r19 post-mortem: 16-wave blocks hit the 32-wave/CU cap -> only 2 barrier
// domains/CU; every __syncthreads convoyed 16 waves behind the slowest
// (70% unhidden stalls). Now: phases A/C give each wave TWO nodes (w, w+8);
// phase B spreads 9 MFMA slices over 8 waves (wave 0 takes s=0 and s=8);
// Abf is ALIASED into the front half of each Osh s-slot (wave s reads its
// A-fragments into registers before writing Osh[s]; slots s-partitioned;
// barriers between phases) -> LDS 58.9K -> 39.2K -> 4 blocks/CU = 4
// independent barrier domains at the 32-wave cap.
// ---------------------------------------------------------------------------
template <int PHASE>
__global__ __launch_bounds__(512) void gather_mix(
    const float4* __restrict__ geoS, const int* __restrict__ srcS,
    const float* __restrict__ Tab,
    const int* __restrict__ start, const int* __restrict__ deg,
    const unsigned short* __restrict__ Wbt,    // [3][64][64] bf16 (this t)
    const float* __restrict__ Wprodt, const int* __restrict__ spec,
    const int* __restrict__ batch,
    const float* __restrict__ Wread0, const float* __restrict__ Wm1,
    const float* __restrict__ wm2,
    const float* __restrict__ Sin, float* __restrict__ Sout,
    float* __restrict__ epart, int N)
{
    __shared__ float Osh[9 * 1088];   // 39168 B; slot s = Osh+s*1088.
    // Abf[s] (16x68 bf16 = 2176 B) aliases the front half of slot s.

    int t = threadIdx.x;
    int lane = t & 63, w = t >> 6;    // w in 0..7
    int l15 = lane & 15, quad = lane >> 4;
    int n0 = blockIdx.x * 16;

    // ---- Phase C prefetch for both nodes (consumed after barriers) ----
    int nn[2] = {n0 + w, n0 + w + 8};
    int b[2] = {0, 0}, sp[2] = {0, 0};
    float resid[2] = {0.f, 0.f};
    #pragma unroll
    for (int j = 0; j < 2; j++) {
        if (nn[j] < N) {
            b[j] = batch[nn[j]];
            sp[j] = spec[nn[j]];
            if (PHASE == 1) resid[j] = Sin[(size_t)nn[j] * F + lane];
        }
    }

    // ---- Phase A: edge accumulation, two nodes per wave (lane = f) ----
    const float s3 = 1.7320508075688772f;
    const float s5h = 1.1180339887498948f;
    const float s15 = 3.8729833462074170f;
    const float s15h = 1.9364916731037085f;
    #pragma unroll
    for (int j = 0; j < 2; j++) {
        int n = nn[j];
        int v = w + j * 8;
        float am[9] = {0.f, 0.f, 0.f, 0.f, 0.f, 0.f, 0.f, 0.f, 0.f};
        if (n < N) {
            int st = start[n], iend = st + deg[n];
            for (int i = st; i < iend; i++) {
                float4 gv = geoS[i];                 // wave-uniform
                int srcn = srcS[i];
                float sv = Sin[(size_t)srcn * F + lane];
                float scaled = gv.w * (NTAB / 5.0f);
                int idx = (int)scaled;
                float fr = scaled - (float)idx;
                const float* T0 = Tab + (size_t)idx * 192;
                float wa = T0[lane],       wb = T0[192 + lane];
                float wc = T0[64 + lane],  wd = T0[256 + lane];
                float we = T0[128 + lane], wf_ = T0[320 + lane];
                float w0 = fmaf(fr, wb - wa, wa);
                float w1 = fmaf(fr, wd - wc, wc);
                float w2 = fmaf(fr, wf_ - we, we);
                float ux = gv.x, uy = gv.y, uz = gv.z;
                float m0 = w0 * sv, m1 = w1 * sv, m2 = w2 * sv;
                am[0] += m0;
                am[1] = fmaf(m1, s3 * ux, am[1]);
                am[2] = fmaf(m1, s3 * uy, am[2]);
                am[3] = fmaf(m1, s3 * uz, am[3]);
                am[4] = fmaf(m2, s15 * ux * uy, am[4]);
                am[5] = fmaf(m2, s15 * uy * uz, am[5]);
                am[6] = fmaf(m2, s5h * (3.0f * uz * uz - 1.0f), am[6]);
                am[7] = fmaf(m2, s15 * ux * uz, am[7]);
                am[8] = fmaf(m2, s15h * (ux * ux - uy * uy), am[8]);
            }
        }
        #pragma unroll
        for (int s = 0; s < 9; s++)
            ((unsigned short*)(Osh + s * 1088))[v * 68 + lane] = f2bf(am[s]);
    }

    // Wprod rows prefetch (in flight across the barriers)
    float wp[2][3] = {{0.f, 0.f, 0.f}, {0.f, 0.f, 0.f}};
    #pragma unroll
    for (int j = 0; j < 2; j++) {
        if (nn[j] < N) {
            const float* W = Wprodt + (sp[j] * F + lane) * 3;
            wp[j][0] = W[0]; wp[j][1] = W[1]; wp[j][2] = W[2];
        }
    }
    __syncthreads();

    // ---- Phase B: MFMA mixing, 9 slices over 8 waves (wave 0: s=0,8) ----
    for (int s = w; s < 9; s += 8) {
        int l = (s == 0) ? 0 : ((s < 4) ? 1 : 2);
        const unsigned short* Bp = Wbt + l * 4096 + (size_t)l15 * 64;
        const unsigned short* Ar =
            (const unsigned short*)(Osh + s * 1088) + l15 * 68;
        short8v a0 = *(const short8v*)(Ar + quad * 8);
        short8v a1 = *(const short8v*)(Ar + 32 + quad * 8);
        #pragma unroll
        for (int nt = 0; nt < 4; nt++) {
            short8v b0 = *(const short8v*)(Bp + nt * 1024 + quad * 8);
            short8v b1 = *(const short8v*)(Bp + nt * 1024 + 32 + quad * 8);
            float4v acc = {0.f, 0.f, 0.f, 0.f};
            acc = __builtin_amdgcn_mfma_f32_16x16x32_bf16(a0, b0, acc, 0, 0, 0);
            acc = __builtin_amdgcn_mfma_f32_16x16x32_bf16(a1, b1, acc, 0, 0, 0);
            #pragma unroll
            for (int r = 0; r < 4; r++)
                Osh[s * 1088 + (quad * 4 + r) * 68 + nt * 16 + l15] = acc[r];
        }
    }
    __syncthreads();

    // ---- Phase C: epilogue, two nodes per wave ----
    #pragma unroll
    for (int j = 0; j < 2; j++) {
        int n = nn[j];
        if (n >= N) continue;
        int v = w + j * 8;
        float bb[9];
        #pragma unroll
        for (int s = 0; s < 9; s++) bb[s] = Osh[s * 1088 + v * 68 + lane];

        float p1 = bb[0];
        float p2 = 0.f;
        #pragma unroll
        for (int s = 0; s < 9; s++) p2 = fmaf(bb[s], bb[s], p2);
        float scale = wp[j][0] + wp[j][1] * p1 + wp[j][2] * p2;
        float sc0 = bb[0] * scale;

        if (PHASE == 0) {
            Sout[(size_t)n * F + lane] = sc0;
            float vv = sc0 * Wread0[lane];
            #pragma unroll
            for (int off = 32; off > 0; off >>= 1) vv += __shfl_xor(vv, off);
            if (lane == 0) atomicAdd(&epart[b[j] * EPW + (n & (EPW - 1))], vv);
        } else {
            sc0 += resid[j];                 // residual (prev channel-0)
            int gi = lane & 15;
            float acc = 0.0f;
            #pragma unroll 8
            for (int k = 0; k < 64; k++)
                acc = fmaf(bcast(sc0, k), Wm1[k * 16 + gi], acc);
            float vv = (lane < 16) ? silu(acc) * wm2[gi] : 0.0f;
            #pragma unroll
            for (int off = 32; off > 0; off >>= 1) vv += __shfl_xor(vv, off);
            if (lane == 0) atomicAdd(&epart[b[j] * EPW + (n & (EPW - 1))], vv);
        }
    }
}

// ---------------------------------------------------------------------------
// Kernel 6: final energy reduction; sole writer of d_out.
// ---------------------------------------------------------------------------
__global__ __launch_bounds__(256) void reduce_energy(
    const float* __restrict__ epart, float* __restrict__ out)
{
    int t = threadIdx.x;
    __shared__ float ps[GSEG][4];
    for (int b = 0; b < GSEG; b++) {
        float v = epart[b * EPW + t];
        #pragma unroll
        for (int off = 32; off > 0; off >>= 1) v += __shfl_xor(v, off);
        if ((t & 63) == 0) ps[b][t >> 6] = v;
    }
    __syncthreads();
    if (t < GSEG) out[t] = ps[t][0] + ps[t][1] + ps[t][2] + ps[t][3];
}

extern "C" void kernel_launch(void* const* d_in, const int* in_sizes, int n_in,
                              void* d_out, int out_size, void* d_ws, size_t ws_size,
                              hipStream_t stream) {
    const float* positions  = (const float*)d_in[0];
    const float* node_attrs = (const float*)d_in[1];
    const float* shifts     = (const float*)d_in[2];
    // d_in[3] charges: unused (charge_density never feeds energy)
    const int*   edge_index = (const int*)d_in[4];
    const int*   batch      = (const int*)d_in[5];
    const float* AE         = (const float*)d_in[6];
    const float* W_embed    = (const float*)d_in[7];
    const float* Wr0        = (const float*)d_in[8];
    const float* Wr1        = (const float*)d_in[9];
    const float* Wr2        = (const float*)d_in[10];
    const float* Wmix       = (const float*)d_in[11];
    const float* Wprod      = (const float*)d_in[12];
    const float* Wread0     = (const float*)d_in[13];
    const float* Wm1        = (const float*)d_in[14];
    const float* wm2        = (const float*)d_in[15];
    // d_in[16] Wq: unused

    int N = in_sizes[0] / 3;
    int E = in_sizes[4] / 2;
    int EB = E / 8;
    float* out = (float*)d_out;

    char* ws = (char*)d_ws;
    size_t off = 0;
    auto alignup = [](size_t v) { return (v + 255) & ~(size_t)255; };
    float4* geoFull = (float4*)(ws + off); off = alignup(off + (size_t)E * sizeof(float4));
    float4* geoS  = (float4*)(ws + off); off = alignup(off + (size_t)EB * sizeof(float4));
    float4* pos4  = (float4*)(ws + off); off = alignup(off + (size_t)N * sizeof(float4));
    float*  S0    = (float*)(ws + off);  off = alignup(off + (size_t)N * F * sizeof(float));
    float*  S1    = (float*)(ws + off);  off = alignup(off + (size_t)N * F * sizeof(float));
    int*    srcS  = (int*)(ws + off);    off = alignup(off + (size_t)EB * sizeof(int));
    int*    deg   = (int*)(ws + off);    off = alignup(off + (size_t)N * sizeof(int));
    int*    start = (int*)(ws + off);    off = alignup(off + (size_t)N * sizeof(int));
    int*    cursor= (int*)(ws + off);    off = alignup(off + (size_t)N * sizeof(int));
    int*    spec  = (int*)(ws + off);    off = alignup(off + (size_t)N * sizeof(int));
    // epart + total share one memset region: total INSIDE the memset range
    // (r15 bug: alignup pushed total past the memset -> poison -> OOB).
    float*  epart = (float*)(ws + off);
    int*    total = (int*)(ws + off + GSEG * EPW * sizeof(float));
    off = alignup(off + GSEG * EPW * sizeof(float) + 128);
    float*  Tab   = (float*)(ws + off);
    off = alignup(off + (size_t)2 * (NTAB + 1) * 192 * sizeof(float));
    unsigned short* Wbt = (unsigned short*)(ws + off);
    off = alignup(off + (size_t)2 * 3 * 4096 * sizeof(unsigned short));
    // total ~22 MB

    hipMemsetAsync(epart, 0, GSEG * EPW * sizeof(float) + 128, stream); // + total

    int nodeBlocks4 = (N + 3) / 4;
    int nodeBlocks256 = (N + 255) / 256;
    int edgeBlocks = (E + 255) / 256;
    int tabBlocks = 2 * ((NTAB + 1 + 3) / 4);
    int wbBlocks = (2 * 3 * 4096 + 255) / 256;
    int gmBlocks = (N + 15) / 16;
    size_t tabStride = (size_t)(NTAB + 1) * 192;

    init_and_tables<<<nodeBlocks4 + tabBlocks + wbBlocks, 256, 0, stream>>>(
        node_attrs, AE, W_embed, batch, positions,
        S0, epart, deg, pos4, spec, N, nodeBlocks4,
        Wr0, Wr1, Wr2, Tab, Wmix, Wbt, tabBlocks);
    edge_prep<<<edgeBlocks, 256, 0, stream>>>(pos4, shifts, edge_index, E,
                                              geoFull, deg);
    alloc_start<<<nodeBlocks256, 256, 0, stream>>>(deg, start, cursor, total, N);
    csr_fill<<<edgeBlocks, 256, 0, stream>>>(geoFull, edge_index, E,
                                             cursor, geoS, srcS, EB);

    // t = 0
    gather_mix<0><<<gmBlocks, 512, 0, stream>>>(geoS, srcS, Tab, start, deg,
                                                Wbt, Wprod, spec, batch,
                                                Wread0, Wm1, wm2,
                                                S0, S1, epart, N);
    // t = 1
    gather_mix<1><<<gmBlocks, 512, 0, stream>>>(geoS, srcS, Tab + tabStride,
                                                start, deg,
                                                Wbt + 3 * 4096,
                                                Wprod + NE * F * 3, spec, batch,
                                                Wread0, Wm1, wm2,
                                                S1, S1, epart, N);

    reduce_energy<<<1, 256, 0, stream>>>(epart, out);
}